// Round 4
// baseline (187.754 us; speedup 1.0000x reference)
//
#include <hip/hip_runtime.h>

// SymmetricContraction: out[n,c,i] = cubic polynomial in x[n,c,:] with
// species/channel-dependent coefficients (968 monomials, padded to 992).
//   coef[s,t,c,0:4] = mult_t * sum_k u[t,k,i] w[s,k,c]
//   out[n,c,i]      = sum_t coef[idx_n,t,c,i] * x_a x_b x_j   (a,b,j from t)
// Pipeline (3 dispatches):
//   coef_setup : coef table (~20 MB in ws) + species-bucketed atom order
//   contract   : per (atomblk, term-chunk, ch-half) eval -> disjoint partials
//                APT=4 atoms/thread, 4-deep double-buffered coef prefetch
//   reduce     : out = sum over 8 chunk partials
// ws requirement: ~29 MiB.

#define DD     16
#define NATOM  512
#define NCH    128
#define NSPEC  10
#define NT3    816
#define NT2    136
#define NT     968
#define NTP    992   // padded to 8 chunks x 124 terms (31 batches of 4)
#define ATB    16    // atoms per eval block (same species)
#define APT    4     // atoms per thread
#define MAXB   42    // >= sum_s ceil(cnt_s/ATB)  (hard bound 41)
#define CHUNKS 8
#define NTC    124   // terms per chunk
#define CHALF  2     // channel halves (64 ch per block)

#define WS_DESC  0
#define WS_ORDER 1024
#define WS_COEF  8192
#define COEF_BYTES (NSPEC * NTP * NCH * 16)       // 20,316,160
#define WS_PART  (WS_COEF + COEF_BYTES)           // partials: 8 x 1 MB

// ---------------- compile-time term table ----------------
// slot semantics for monomial factors: 0..15 -> x[d], 16 -> 1.0f, 17 -> 0.0f
struct TermTable { unsigned v[NTP]; };
constexpr TermTable build_terms() {
  TermTable T{};
  int t = 0;
  for (int a = 0; a < DD; a++)
    for (int b = a; b < DD; b++)
      for (int j = b; j < DD; j++) T.v[t++] = (unsigned)(a | (b << 5) | (j << 10));
  for (int a = 0; a < DD; a++)
    for (int b = a; b < DD; b++) T.v[t++] = (unsigned)(a | (b << 5) | (16 << 10));
  for (int a = 0; a < DD; a++) T.v[t++] = (unsigned)(a | (16 << 5) | (16 << 10));
  while (t < NTP) T.v[t++] = (unsigned)(17 | (17 << 5) | (17 << 10));
  return T;
}
constexpr TermTable TERMS = build_terms();

// ---------------- runtime term decode (coef kernel only) ----------------
__device__ __forceinline__ void decode_term(int t, int& kind, int& a, int& b,
                                            int& j, int& mult) {
  a = 0; b = 0; j = 0;
  if (t < NT3) {
    kind = 3;
    int r = t;
    for (a = 0; a < DD; a++) { int ca = (DD - a) * (DD - a + 1) / 2; if (r < ca) break; r -= ca; }
    for (b = a; b < DD; b++) { int cb = DD - b; if (r < cb) break; r -= cb; }
    j = b + r;
    mult = (a == b && b == j) ? 1 : ((a == b || b == j) ? 3 : 6);
  } else if (t < NT3 + NT2) {
    kind = 2;
    int r = t - NT3;
    for (a = 0; a < DD; a++) { int ca = DD - a; if (r < ca) break; r -= ca; }
    b = a + r;
    mult = (a == b) ? 1 : 2;
  } else {
    kind = 1; a = t - NT3 - NT2; mult = 1;
  }
}

// ---------------- setup: species bucketing (run by one coef block) -------
__device__ void do_setup(const int* __restrict__ index, int* __restrict__ desc,
                         int* __restrict__ order) {
  __shared__ int cnt[NSPEC], cursor[NSPEC], bbase[NSPEC + 1];
  const int tid = threadIdx.x;  // 0..127
  if (tid < NSPEC) { cnt[tid] = 0; cursor[tid] = 0; }
  __syncthreads();
  for (int i = tid; i < NATOM; i += 128) atomicAdd(&cnt[index[i]], 1);
  for (int i = tid; i < MAXB * ATB; i += 128) order[i] = -1;
  __syncthreads();
  if (tid == 0) {
    int base = 0;
    for (int s = 0; s < NSPEC; s++) { bbase[s] = base; base += (cnt[s] + ATB - 1) / ATB; }
    bbase[NSPEC] = base;
  }
  __syncthreads();
  for (int i = tid; i < NATOM; i += 128) {
    int s = index[i];
    int pos = atomicAdd(&cursor[s], 1);
    order[bbase[s] * ATB + pos] = i;
  }
  for (int i = tid; i < MAXB; i += 128) {
    int sp = -1;
    for (int s = 0; s < NSPEC; s++)
      if (i >= bbase[s] && i < bbase[s + 1]) sp = s;
    desc[i] = sp;
  }
}

// ---------------- coefficient build (+fused setup) ----------------
__global__ __launch_bounds__(128) void coef_setup_kernel(
    const float* __restrict__ u3_0, const float* __restrict__ w3_0,
    const float* __restrict__ u2_0, const float* __restrict__ w2_0,
    const float* __restrict__ u1_0, const float* __restrict__ w1_0,
    const float* __restrict__ u3_1, const float* __restrict__ w3_1,
    const float* __restrict__ u2_1, const float* __restrict__ w2_1,
    const float* __restrict__ u1_1, const float* __restrict__ w1_1,
    const int* __restrict__ index, int* __restrict__ desc,
    int* __restrict__ order, float* __restrict__ coef) {
  if (blockIdx.y == NTP / 4) {                 // setup row
    if (blockIdx.x == 0) do_setup(index, desc, order);
    return;
  }
  const int s = blockIdx.x;
  const int c = threadIdx.x;
  const int tbase = blockIdx.y * 4;

  float r3_0[23], r3_1[33], r2_0[4], r2_1[6];
#pragma unroll
  for (int k = 0; k < 23; k++) r3_0[k] = w3_0[(s * 23 + k) * NCH + c];
#pragma unroll
  for (int k = 0; k < 33; k++) r3_1[k] = w3_1[(s * 33 + k) * NCH + c];
#pragma unroll
  for (int k = 0; k < 4; k++) r2_0[k] = w2_0[(s * 4 + k) * NCH + c];
#pragma unroll
  for (int k = 0; k < 6; k++) r2_1[k] = w2_1[(s * 6 + k) * NCH + c];
  const float r1_0 = w1_0[s * NCH + c];
  const float r1_1 = w1_1[s * NCH + c];

  for (int tt = 0; tt < 4; tt++) {
    const int t = tbase + tt;
    float4 cf{0.f, 0.f, 0.f, 0.f};
    if (t < NT) {
      int kind, a, b, j, mult;
      decode_term(t, kind, a, b, j, mult);
      float s0 = 0.f, s1 = 0.f, s2 = 0.f, s3 = 0.f;
      if (kind == 3) {
        const float* u0p = u3_0 + ((a * DD + b) * DD + j) * 23;
#pragma unroll
        for (int k = 0; k < 23; k++) s0 += u0p[k] * r3_0[k];
        const float* u1p = u3_1 + ((size_t)((a * DD + b) * DD + j)) * 99;
#pragma unroll
        for (int k = 0; k < 33; k++) {
          const float w = r3_1[k];
          s1 += u1p[k * 3 + 0] * w;
          s2 += u1p[k * 3 + 1] * w;
          s3 += u1p[k * 3 + 2] * w;
        }
      } else if (kind == 2) {
        const float* u0p = u2_0 + (a * DD + b) * 4;
#pragma unroll
        for (int k = 0; k < 4; k++) s0 += u0p[k] * r2_0[k];
        const float* u1p = u2_1 + (a * DD + b) * 18;
#pragma unroll
        for (int k = 0; k < 6; k++) {
          const float w = r2_1[k];
          s1 += u1p[k * 3 + 0] * w;
          s2 += u1p[k * 3 + 1] * w;
          s3 += u1p[k * 3 + 2] * w;
        }
      } else {
        s0 = u1_0[a] * r1_0;
        s1 = u1_1[a * 3 + 0] * r1_1;
        s2 = u1_1[a * 3 + 1] * r1_1;
        s3 = u1_1[a * 3 + 2] * r1_1;
      }
      const float fm = (float)mult;
      cf = float4{fm * s0, fm * s1, fm * s2, fm * s3};
    }
    *(float4*)(coef + ((size_t)(s * NTP + t) * NCH + c) * 4) = cf;
  }
}

// ---------------- polynomial evaluation ----------------
template <int CH>
__device__ __forceinline__ void accum_chunk(const float* __restrict__ cp,
                                            const float (&xr)[APT][18],
                                            float (&ac)[APT][4]) {
  constexpr int T0 = CH * NTC;
  constexpr int BT = 4;          // terms per batch
  constexpr int NG = NTC / BT;   // 31 batches
  constexpr int TS = NCH * 4;    // float stride between terms

  float4 buf[2][BT];
#pragma unroll
  for (int i = 0; i < BT; i++)
    buf[0][i] = *(const float4*)(cp + (size_t)(T0 + i) * TS);

#pragma unroll
  for (int g = 0; g < NG; g++) {
    const int cur = g & 1, nxt = cur ^ 1;
    if (g + 1 < NG) {
#pragma unroll
      for (int i = 0; i < BT; i++)
        buf[nxt][i] = *(const float4*)(cp + (size_t)(T0 + (g + 1) * BT + i) * TS);
    }
#pragma unroll
    for (int i = 0; i < BT; i++) {
      const unsigned ev = TERMS.v[T0 + g * BT + i];  // folds to constant
      const int ea = ev & 31, eb = (ev >> 5) & 31, ej = (ev >> 10) & 31;
      const float4 cf = buf[cur][i];
#pragma unroll
      for (int k = 0; k < APT; k++) {
        const float m = xr[k][ea] * xr[k][eb] * xr[k][ej];
        ac[k][0] += cf.x * m; ac[k][1] += cf.y * m;
        ac[k][2] += cf.z * m; ac[k][3] += cf.w * m;
      }
    }
  }
}

__device__ __forceinline__ void load16(float (&xr)[18], const float* __restrict__ p) {
  const float4* q = (const float4*)p;
  const float4 v0 = q[0], v1 = q[1], v2 = q[2], v3 = q[3];
  xr[0] = v0.x; xr[1] = v0.y; xr[2] = v0.z; xr[3] = v0.w;
  xr[4] = v1.x; xr[5] = v1.y; xr[6] = v1.z; xr[7] = v1.w;
  xr[8] = v2.x; xr[9] = v2.y; xr[10] = v2.z; xr[11] = v2.w;
  xr[12] = v3.x; xr[13] = v3.y; xr[14] = v3.z; xr[15] = v3.w;
}

__global__ __launch_bounds__(256, 4) void contract_kernel(const float* __restrict__ x,
                                                          const int* __restrict__ desc,
                                                          const int* __restrict__ order,
                                                          const float* __restrict__ coef,
                                                          float* __restrict__ partial) {
  const int s = desc[blockIdx.x];
  if (s < 0) return;
  const int cl = threadIdx.x & 63;
  const int g  = threadIdx.x >> 6;            // 0..3 -> atoms 4g..4g+3
  const int c  = blockIdx.z * 64 + cl;

  int n[APT];
#pragma unroll
  for (int k = 0; k < APT; k++) n[k] = order[blockIdx.x * ATB + g * APT + k];

  float xr[APT][18];
#pragma unroll
  for (int k = 0; k < APT; k++) {
#pragma unroll
    for (int i = 0; i < DD; i++) xr[k][i] = 0.f;
    xr[k][16] = 1.f;   // slot for pair/linear terms
    xr[k][17] = 0.f;   // slot for pad terms
  }
#pragma unroll
  for (int k = 0; k < APT; k++)
    if (n[k] >= 0) load16(xr[k], x + ((size_t)n[k] * NCH + c) * DD);

  float ac[APT][4];
#pragma unroll
  for (int k = 0; k < APT; k++) { ac[k][0] = 0.f; ac[k][1] = 0.f; ac[k][2] = 0.f; ac[k][3] = 0.f; }

  const float* cp = coef + ((size_t)s * NTP * NCH + (size_t)c) * 4;

  switch (blockIdx.y) {
    case 0: accum_chunk<0>(cp, xr, ac); break;
    case 1: accum_chunk<1>(cp, xr, ac); break;
    case 2: accum_chunk<2>(cp, xr, ac); break;
    case 3: accum_chunk<3>(cp, xr, ac); break;
    case 4: accum_chunk<4>(cp, xr, ac); break;
    case 5: accum_chunk<5>(cp, xr, ac); break;
    case 6: accum_chunk<6>(cp, xr, ac); break;
    default: accum_chunk<7>(cp, xr, ac); break;
  }

  float* pb = partial + (size_t)blockIdx.y * (NATOM * NCH * 4);
#pragma unroll
  for (int k = 0; k < APT; k++)
    if (n[k] >= 0)
      *(float4*)(pb + ((size_t)n[k] * NCH + c) * 4) =
          float4{ac[k][0], ac[k][1], ac[k][2], ac[k][3]};
}

// ---------------- final reduction over chunks ----------------
__global__ __launch_bounds__(256) void reduce_kernel(const float4* __restrict__ partial,
                                                     float4* __restrict__ out) {
  const int i = blockIdx.x * 256 + threadIdx.x;  // 0 .. NATOM*NCH-1
  float4 s{0.f, 0.f, 0.f, 0.f};
#pragma unroll
  for (int ch = 0; ch < CHUNKS; ch++) {
    const float4 v = partial[(size_t)ch * (NATOM * NCH) + i];
    s.x += v.x; s.y += v.y; s.z += v.z; s.w += v.w;
  }
  out[i] = s;
}

extern "C" void kernel_launch(void* const* d_in, const int* in_sizes, int n_in,
                              void* d_out, int out_size, void* d_ws, size_t ws_size,
                              hipStream_t stream) {
  const float* x    = (const float*)d_in[0];
  const int* index  = (const int*)d_in[1];
  const float* u3_0 = (const float*)d_in[2];
  const float* w3_0 = (const float*)d_in[3];
  const float* u2_0 = (const float*)d_in[4];
  const float* w2_0 = (const float*)d_in[5];
  const float* u1_0 = (const float*)d_in[6];
  const float* w1_0 = (const float*)d_in[7];
  const float* u3_1 = (const float*)d_in[8];
  const float* w3_1 = (const float*)d_in[9];
  const float* u2_1 = (const float*)d_in[10];
  const float* w2_1 = (const float*)d_in[11];
  const float* u1_1 = (const float*)d_in[12];
  const float* w1_1 = (const float*)d_in[13];
  float* out = (float*)d_out;

  char* ws = (char*)d_ws;
  int* desc      = (int*)(ws + WS_DESC);
  int* order     = (int*)(ws + WS_ORDER);
  float* coef    = (float*)(ws + WS_COEF);
  float* partial = (float*)(ws + WS_PART);

  coef_setup_kernel<<<dim3(NSPEC, NTP / 4 + 1), 128, 0, stream>>>(
      u3_0, w3_0, u2_0, w2_0, u1_0, w1_0,
      u3_1, w3_1, u2_1, w2_1, u1_1, w1_1, index, desc, order, coef);
  contract_kernel<<<dim3(MAXB, CHUNKS, CHALF), 256, 0, stream>>>(x, desc, order, coef, partial);
  reduce_kernel<<<(NATOM * NCH) / 256, 256, 0, stream>>>((const float4*)partial, (float4*)out);
}

// Round 5
// 155.828 us; speedup vs baseline: 1.2049x; 1.2049x over previous
//
#include <hip/hip_runtime.h>

// SymmetricContraction: out[n,c,i] = cubic polynomial in x[n,c,:] with
// species/channel-dependent coefficients (968 monomials, padded to 1024).
//   coef[s,t,c,0:4] = mult_t * sum_k u[t,k,i] w[s,k,c]
//   out[n,c,i]      = sum_t coef[idx_n,t,c,i] * x_a x_b x_j
// Pipeline (3 dispatches):
//   coef_setup : coef table (~21 MB ws), u staged in LDS cooperatively;
//                + species-bucketed atom order (one spare block)
//   contract   : m97-style LDS pipeline — coef tiles streamed via
//                global_load_lds (16B, async) double-buffered; APT=4
//   reduce     : out = sum over 8 chunk partials
// ws requirement: ~29.4 MiB.

#define DD     16
#define NATOM  512
#define NCH    128
#define NSPEC  10
#define NT3    816
#define NT2    136
#define NT     968
#define NTP    1024  // 8 chunks x 128 terms
#define ATB    16    // atoms per eval block (same species)
#define APT    4     // atoms per thread
#define MAXB   42    // >= sum_s ceil(cnt_s/ATB)
#define CHUNKS 8
#define NTC    128   // terms per chunk
#define TILE   8     // terms per LDS tile
#define NTILES (NTC / TILE)  // 16
#define CHALF  2     // channel halves (64 ch per block)
#define CT     16    // terms per coef block

#define WS_DESC  0
#define WS_ORDER 1024
#define WS_COEF  8192
#define COEF_BYTES (NSPEC * NTP * NCH * 16)       // 20,971,520
#define WS_PART  (WS_COEF + COEF_BYTES)           // partials: 8 x 1 MB

// ---------------- compile-time term table ----------------
// pack: a | b<<5 | j<<10 | kind<<15 | mult<<18
// slots in contract: 0..15 -> x[d], 16 -> 1.0f, 17 -> 0.0f
struct TermTable { unsigned v[NTP]; };
constexpr TermTable build_terms() {
  TermTable T{};
  int t = 0;
  for (int a = 0; a < DD; a++)
    for (int b = a; b < DD; b++)
      for (int j = b; j < DD; j++) {
        unsigned m = (a == b && b == j) ? 1u : ((a == b || b == j) ? 3u : 6u);
        T.v[t++] = (unsigned)(a | (b << 5) | (j << 10) | (3u << 15) | (m << 18));
      }
  for (int a = 0; a < DD; a++)
    for (int b = a; b < DD; b++) {
      unsigned m = (a == b) ? 1u : 2u;
      T.v[t++] = (unsigned)(a | (b << 5) | (16 << 10) | (2u << 15) | (m << 18));
    }
  for (int a = 0; a < DD; a++)
    T.v[t++] = (unsigned)(a | (16 << 5) | (16 << 10) | (1u << 15) | (1u << 18));
  while (t < NTP) T.v[t++] = (unsigned)(17 | (17 << 5) | (17 << 10));
  return T;
}
constexpr TermTable TERMS = build_terms();

// ---------------- setup: species bucketing ----------------
__device__ void do_setup(const int* __restrict__ index, int* __restrict__ desc,
                         int* __restrict__ order) {
  __shared__ int cnt[NSPEC], cursor[NSPEC], bbase[NSPEC + 1];
  const int tid = threadIdx.x;  // 0..127
  if (tid < NSPEC) { cnt[tid] = 0; cursor[tid] = 0; }
  __syncthreads();
  for (int i = tid; i < NATOM; i += 128) atomicAdd(&cnt[index[i]], 1);
  for (int i = tid; i < MAXB * ATB; i += 128) order[i] = -1;
  __syncthreads();
  if (tid == 0) {
    int base = 0;
    for (int s = 0; s < NSPEC; s++) { bbase[s] = base; base += (cnt[s] + ATB - 1) / ATB; }
    bbase[NSPEC] = base;
  }
  __syncthreads();
  for (int i = tid; i < NATOM; i += 128) {
    int s = index[i];
    int pos = atomicAdd(&cursor[s], 1);
    order[bbase[s] * ATB + pos] = i;
  }
  for (int i = tid; i < MAXB; i += 128) {
    int sp = -1;
    for (int s = 0; s < NSPEC; s++)
      if (i >= bbase[s] && i < bbase[s + 1]) sp = s;
    desc[i] = sp;
  }
}

// ---------------- coefficient build (+fused setup) ----------------
__global__ __launch_bounds__(128) void coef_setup_kernel(
    const float* __restrict__ u3_0, const float* __restrict__ w3_0,
    const float* __restrict__ u2_0, const float* __restrict__ w2_0,
    const float* __restrict__ u1_0, const float* __restrict__ w1_0,
    const float* __restrict__ u3_1, const float* __restrict__ w3_1,
    const float* __restrict__ u2_1, const float* __restrict__ w2_1,
    const float* __restrict__ u1_1, const float* __restrict__ w1_1,
    const int* __restrict__ index, int* __restrict__ desc,
    int* __restrict__ order, float* __restrict__ coef) {
  if (blockIdx.y == NTP / CT) {                // spare row: setup
    if (blockIdx.x == 0) do_setup(index, desc, order);
    return;
  }
  const int s = blockIdx.x;
  const int c = threadIdx.x;
  const int tbase = blockIdx.y * CT;

  __shared__ float us0[CT][23];
  __shared__ float us1[CT][99];

  // cooperative u staging (coalesced; addresses uniform per term, lane-split)
  for (int i = 0; i < CT; ++i) {
    const unsigned ev = TERMS.v[tbase + i];
    const int kind = (ev >> 15) & 7;
    const int a = ev & 31, b = (ev >> 5) & 31, j = (ev >> 10) & 31;
    if (kind == 3) {
      const int off = (a * DD + b) * DD + j;
      if (c < 23) us0[i][c] = u3_0[off * 23 + c];
      else if (c < 122) us1[i][c - 23] = u3_1[(size_t)off * 99 + (c - 23)];
    } else if (kind == 2) {
      const int off = a * DD + b;
      if (c < 4) us0[i][c] = u2_0[off * 4 + c];
      else if (c < 22) us1[i][c - 4] = u2_1[off * 18 + (c - 4)];
    } else if (kind == 1) {
      if (c < 1) us0[i][0] = u1_0[a];
      else if (c < 4) us1[i][c - 1] = u1_1[a * 3 + (c - 1)];
    }
  }
  __syncthreads();

  float r3_0[23], r3_1[33], r2_0[4], r2_1[6];
#pragma unroll
  for (int k = 0; k < 23; k++) r3_0[k] = w3_0[(s * 23 + k) * NCH + c];
#pragma unroll
  for (int k = 0; k < 33; k++) r3_1[k] = w3_1[(s * 33 + k) * NCH + c];
#pragma unroll
  for (int k = 0; k < 4; k++) r2_0[k] = w2_0[(s * 4 + k) * NCH + c];
#pragma unroll
  for (int k = 0; k < 6; k++) r2_1[k] = w2_1[(s * 6 + k) * NCH + c];
  const float r1_0 = w1_0[s * NCH + c];
  const float r1_1 = w1_1[s * NCH + c];

  for (int i = 0; i < CT; ++i) {
    const unsigned ev = TERMS.v[tbase + i];
    const int kind = (ev >> 15) & 7;
    const float fm = (float)((ev >> 18) & 7);
    float s0 = 0.f, s1 = 0.f, s2 = 0.f, s3 = 0.f;
    if (kind == 3) {
#pragma unroll
      for (int k = 0; k < 23; k++) s0 += us0[i][k] * r3_0[k];
#pragma unroll
      for (int k = 0; k < 33; k++) {
        const float w = r3_1[k];
        s1 += us1[i][k * 3 + 0] * w;
        s2 += us1[i][k * 3 + 1] * w;
        s3 += us1[i][k * 3 + 2] * w;
      }
    } else if (kind == 2) {
#pragma unroll
      for (int k = 0; k < 4; k++) s0 += us0[i][k] * r2_0[k];
#pragma unroll
      for (int k = 0; k < 6; k++) {
        const float w = r2_1[k];
        s1 += us1[i][k * 3 + 0] * w;
        s2 += us1[i][k * 3 + 1] * w;
        s3 += us1[i][k * 3 + 2] * w;
      }
    } else if (kind == 1) {
      s0 = us0[i][0] * r1_0;
      s1 = us1[i][0] * r1_1;
      s2 = us1[i][1] * r1_1;
      s3 = us1[i][2] * r1_1;
    }
    *(float4*)(coef + ((size_t)(s * NTP + tbase + i) * NCH + c) * 4) =
        float4{fm * s0, fm * s1, fm * s2, fm * s3};
  }
}

// ---------------- contract: LDS-pipelined polynomial eval ----------------
__device__ __forceinline__ void stage_tile(const float* __restrict__ lane_base,
                                           int t0_tile, float* dst_base, int wave) {
#pragma unroll
  for (int r = 0; r < 2; ++r) {
    const int term = wave * 2 + r;                  // 4 waves x 2 = 8 terms
    const float* g = lane_base + (size_t)(t0_tile + term) * (NCH * 4);
    float* l = dst_base + term * 256;               // 64 lanes x 4 floats
    __builtin_amdgcn_global_load_lds(
        (const __attribute__((address_space(1))) unsigned int*)g,
        (__attribute__((address_space(3))) unsigned int*)l, 16, 0, 0);
  }
}

template <int CH>
__device__ __forceinline__ void eval_chunk(const float* __restrict__ lane_base,
                                           float (*lbuf)[TILE * 256],
                                           int wave, int lane,
                                           const float (&xr)[APT][18],
                                           float (&ac)[APT][4]) {
  constexpr int T0 = CH * NTC;
  stage_tile(lane_base, T0, &lbuf[0][0], wave);
#pragma unroll
  for (int tile = 0; tile < NTILES; ++tile) {
    __syncthreads();  // drains vmcnt -> lbuf[tile&1] ready; prev compute done
    if (tile + 1 < NTILES)
      stage_tile(lane_base, T0 + (tile + 1) * TILE, &lbuf[(tile + 1) & 1][0], wave);
    const float* lb = &lbuf[tile & 1][0];
#pragma unroll
    for (int i = 0; i < TILE; ++i) {
      const unsigned ev = TERMS.v[T0 + tile * TILE + i];  // compile-time const
      const int ea = ev & 31, eb = (ev >> 5) & 31, ej = (ev >> 10) & 31;
      const float4 cf = *(const float4*)(lb + (i * 64 + lane) * 4);
#pragma unroll
      for (int k = 0; k < APT; ++k) {
        const float m = xr[k][ea] * xr[k][eb] * xr[k][ej];
        ac[k][0] += cf.x * m; ac[k][1] += cf.y * m;
        ac[k][2] += cf.z * m; ac[k][3] += cf.w * m;
      }
    }
  }
}

__device__ __forceinline__ void load16(float (&xr)[18], const float* __restrict__ p) {
  const float4* q = (const float4*)p;
  const float4 v0 = q[0], v1 = q[1], v2 = q[2], v3 = q[3];
  xr[0] = v0.x; xr[1] = v0.y; xr[2] = v0.z; xr[3] = v0.w;
  xr[4] = v1.x; xr[5] = v1.y; xr[6] = v1.z; xr[7] = v1.w;
  xr[8] = v2.x; xr[9] = v2.y; xr[10] = v2.z; xr[11] = v2.w;
  xr[12] = v3.x; xr[13] = v3.y; xr[14] = v3.z; xr[15] = v3.w;
}

__global__ __launch_bounds__(256, 4) void contract_kernel(const float* __restrict__ x,
                                                          const int* __restrict__ desc,
                                                          const int* __restrict__ order,
                                                          const float* __restrict__ coef,
                                                          float* __restrict__ partial) {
  const int s = desc[blockIdx.x];
  if (s < 0) return;                           // uniform per block
  const int lane = threadIdx.x & 63;
  const int wave = threadIdx.x >> 6;           // == atom group 0..3
  const int c = blockIdx.z * 64 + lane;

  __shared__ float lbuf[2][TILE * 256];        // 2 x 8 KB

  int n[APT];
#pragma unroll
  for (int k = 0; k < APT; k++) n[k] = order[blockIdx.x * ATB + wave * APT + k];

  float xr[APT][18];
#pragma unroll
  for (int k = 0; k < APT; k++) {
#pragma unroll
    for (int i = 0; i < DD; i++) xr[k][i] = 0.f;
    xr[k][16] = 1.f;
    xr[k][17] = 0.f;
  }
#pragma unroll
  for (int k = 0; k < APT; k++)
    if (n[k] >= 0) load16(xr[k], x + ((size_t)n[k] * NCH + c) * DD);

  float ac[APT][4];
#pragma unroll
  for (int k = 0; k < APT; k++) { ac[k][0] = 0.f; ac[k][1] = 0.f; ac[k][2] = 0.f; ac[k][3] = 0.f; }

  const float* lane_base = coef + ((size_t)s * NTP * NCH + (size_t)blockIdx.z * 64 + lane) * 4;

  switch (blockIdx.y) {
    case 0: eval_chunk<0>(lane_base, lbuf, wave, lane, xr, ac); break;
    case 1: eval_chunk<1>(lane_base, lbuf, wave, lane, xr, ac); break;
    case 2: eval_chunk<2>(lane_base, lbuf, wave, lane, xr, ac); break;
    case 3: eval_chunk<3>(lane_base, lbuf, wave, lane, xr, ac); break;
    case 4: eval_chunk<4>(lane_base, lbuf, wave, lane, xr, ac); break;
    case 5: eval_chunk<5>(lane_base, lbuf, wave, lane, xr, ac); break;
    case 6: eval_chunk<6>(lane_base, lbuf, wave, lane, xr, ac); break;
    default: eval_chunk<7>(lane_base, lbuf, wave, lane, xr, ac); break;
  }

  float* pb = partial + (size_t)blockIdx.y * (NATOM * NCH * 4);
#pragma unroll
  for (int k = 0; k < APT; k++)
    if (n[k] >= 0)
      *(float4*)(pb + ((size_t)n[k] * NCH + c) * 4) =
          float4{ac[k][0], ac[k][1], ac[k][2], ac[k][3]};
}

// ---------------- final reduction over chunks ----------------
__global__ __launch_bounds__(256) void reduce_kernel(const float4* __restrict__ partial,
                                                     float4* __restrict__ out) {
  const int i = blockIdx.x * 256 + threadIdx.x;  // 0 .. NATOM*NCH-1
  float4 s{0.f, 0.f, 0.f, 0.f};
#pragma unroll
  for (int ch = 0; ch < CHUNKS; ch++) {
    const float4 v = partial[(size_t)ch * (NATOM * NCH) + i];
    s.x += v.x; s.y += v.y; s.z += v.z; s.w += v.w;
  }
  out[i] = s;
}

extern "C" void kernel_launch(void* const* d_in, const int* in_sizes, int n_in,
                              void* d_out, int out_size, void* d_ws, size_t ws_size,
                              hipStream_t stream) {
  const float* x    = (const float*)d_in[0];
  const int* index  = (const int*)d_in[1];
  const float* u3_0 = (const float*)d_in[2];
  const float* w3_0 = (const float*)d_in[3];
  const float* u2_0 = (const float*)d_in[4];
  const float* w2_0 = (const float*)d_in[5];
  const float* u1_0 = (const float*)d_in[6];
  const float* w1_0 = (const float*)d_in[7];
  const float* u3_1 = (const float*)d_in[8];
  const float* w3_1 = (const float*)d_in[9];
  const float* u2_1 = (const float*)d_in[10];
  const float* w2_1 = (const float*)d_in[11];
  const float* u1_1 = (const float*)d_in[12];
  const float* w1_1 = (const float*)d_in[13];
  float* out = (float*)d_out;

  char* ws = (char*)d_ws;
  int* desc      = (int*)(ws + WS_DESC);
  int* order     = (int*)(ws + WS_ORDER);
  float* coef    = (float*)(ws + WS_COEF);
  float* partial = (float*)(ws + WS_PART);

  coef_setup_kernel<<<dim3(NSPEC, NTP / CT + 1), 128, 0, stream>>>(
      u3_0, w3_0, u2_0, w2_0, u1_0, w1_0,
      u3_1, w3_1, u2_1, w2_1, u1_1, w1_1, index, desc, order, coef);
  contract_kernel<<<dim3(MAXB, CHUNKS, CHALF), 256, 0, stream>>>(x, desc, order, coef, partial);
  reduce_kernel<<<(NATOM * NCH) / 256, 256, 0, stream>>>((const float4*)partial, (float4*)out);
}